// Round 9
// baseline (187.051 us; speedup 1.0000x reference)
//
#include <hip/hip_runtime.h>
#include <limits.h>

// ---------------- problem constants ----------------
#define BATCH   8
#define LSEQ    1048576          // 1<<20
#define KCONV   500
#define TWIN    2097             // (L-K)/K + 1
#define MROWS   16776            // BATCH*TWIN
#define KDIM    4000             // KCONV * C_IN
#define NDIM    256              // 2 * C_OUT
#define COUT    128
#define VOCAB   257
#define VOCABP  256              // padding row of emb (zeros)

#define BMR     80               // m-rows per block (5 x 16)
#define NTILE   210              // ceil(MROWS/80): fits 256 CUs, no serial tail
#define SLABP   20               // positions per slab = 160 k = 5 BK32 iters
#define NSLAB   25
#define NG      125              // total BK32 iterations
#define PLANE   (NDIM * 32)      // 8192 shorts per g-plane of Wtf
#define AROWSH  168              // padded shorts per A-slab row (160 + 8)
#define STAGEN  (BMR * SLABP)    // 1600 gathers per slab

// ---------------- ws layout (bytes) ----------------
#define WTF_OFF   0ull
#define WTF_BYTES ((size_t)NG * PLANE * 2)                  // 2,048,000
#define POOL_OFF  (WTF_OFF + WTF_BYTES)                     // 1024 floats + flag

typedef __attribute__((ext_vector_type(8))) __bf16 bf16x8;
typedef __attribute__((ext_vector_type(4))) float  floatx4;

__device__ inline unsigned short f2bf(float f) {
    union { float f; unsigned u; } c; c.f = f;
    return (unsigned short)((c.u + 0x7FFFu + ((c.u >> 16) & 1u)) >> 16);
}
__device__ inline unsigned pack2(float lo, float hi) {
    return (unsigned)f2bf(lo) | ((unsigned)f2bf(hi) << 16);
}

// barrier that waits ONLY for LDS ops — leaves global (B/x prefetch) loads in flight
#define LDS_BARRIER() asm volatile("s_waitcnt lgkmcnt(0)\n\ts_barrier" ::: "memory")

// ---------------- kernel 1: frag-major weights + zero pool/flag ----------------
// Wtf[g][n][kk] = w_n[e=(g*32+kk)&7][p=(g*32+kk)>>3]
__global__ __launch_bounds__(256) void wprep_kernel(const float* __restrict__ w1,
                                                    const float* __restrict__ w2,
                                                    unsigned short* __restrict__ Wtf,
                                                    float* __restrict__ pool) {
    const int n   = blockIdx.x;                        // 0..255
    const int tid = threadIdx.x;
    __shared__ float tile[KDIM];                       // 16 KB
    const float* src = (n < COUT) ? (w1 + (size_t)n * KDIM)
                                  : (w2 + (size_t)(n - COUT) * KDIM);
    for (int i = tid; i < KDIM; i += 256) tile[i] = src[i];
    __syncthreads();
    for (int i = tid; i < KDIM; i += 256) {
        int g = i >> 5, kk = i & 31;
        Wtf[(size_t)g * PLANE + n * 32 + kk] = f2bf(tile[(i & 7) * KCONV + (i >> 3)]);
    }
    if (n == 0)
        for (int i = tid; i < BATCH * COUT + 1; i += 256) pool[i] = 0.0f;  // +flag
}

// ---------------- kernel 2: fused embed + full-K GEMM + gate + max-pool + head ----------------
// Grid 210 x 512 thr (8 waves). Wave wv, lane (r16,q): o = wv*16 + r16 (0..127);
// acc[i][0]=c1, acc[i][1]=c2 (n=o+128) -> gate fully in registers.
// A: LDS emb table (gathers via 32-bank crossbar), slab-staged double buffer.
//    af LDS reads SOFTWARE-PIPELINED (ping-pong afp[2][5]) so ds_read latency
//    hides under the previous kt's MFMAs.
// B: frag-major Wtf, coalesced 1KB register loads, depth-2 prefetch; LDS_BARRIER
//    (lgkm-only) never drains them.
// Head: last block (ticket) computes the 128x128 dense + sigmoid.
__global__ __launch_bounds__(512, 2) void gemm_kernel(const int* __restrict__ x,
                                                      const float* __restrict__ emb,
                                                      const unsigned short* __restrict__ Wtf,
                                                      const float* __restrict__ b1,
                                                      const float* __restrict__ b2,
                                                      float* __restrict__ pool,
                                                      const float* __restrict__ wd1,
                                                      const float* __restrict__ bd1,
                                                      const float* __restrict__ wd2,
                                                      const float* __restrict__ bd2,
                                                      float* __restrict__ out) {
    __shared__ unsigned short tableL[VOCAB * 8];       // 4112 B
    __shared__ unsigned short As[2][BMR * AROWSH];     // 2 x 26.25 KB

    const int tid  = threadIdx.x;
    const int lane = tid & 63;
    const int wv   = tid >> 6;                         // 0..7
    const int m0   = blockIdx.x * BMR;
    const int r16  = lane & 15;
    const int q    = lane >> 4;                        // 0..3

    // ---- build bf16 emb table in LDS ----
    if (tid < VOCAB) {
        const float4* er = (const float4*)(emb + tid * 8);
        float4 a = er[0], b = er[1];
        uint4 u;
        u.x = pack2(a.x, a.y); u.y = pack2(a.z, a.w);
        u.z = pack2(b.x, b.y); u.w = pack2(b.z, b.w);
        *(uint4*)(tableL + tid * 8) = u;
    }

    // ---- staging roles: thread handles idx = tid + 512*l (idx < 1600) ----
    const int* xptr[4];
    int        loff[4];
    bool       sval[4];
#pragma unroll
    for (int l = 0; l < 4; ++l) {
        int idx = tid + 512 * l;
        sval[l] = (idx < STAGEN);
        int ic  = sval[l] ? idx : 0;
        int row = ic / SLABP;
        int pos = ic - row * SLABP;
        int am  = m0 + row;
        bool av = sval[l] && (am < MROWS);
        sval[l] = av;
        int amc = av ? am : 0;
        int b   = amc / TWIN;
        int t   = amc - b * TWIN;
        xptr[l] = x + ((size_t)b * LSEQ + (size_t)t * KCONV + pos);
        loff[l] = row * AROWSH + pos * 8;
    }

    // ---- compute role ----
    const int o = wv * 16 + r16;                       // 0..127
    const size_t boff0 = (size_t)o * 32 + q * 8;
    const size_t boff1 = (size_t)(o + 128) * 32 + q * 8;

    floatx4 acc[5][2];
#pragma unroll
    for (int i = 0; i < 5; ++i) { acc[i][0] = floatx4{0,0,0,0}; acc[i][1] = floatx4{0,0,0,0}; }

    // ---- x values for slab 0 ----
    int xv[4];
#pragma unroll
    for (int l = 0; l < 4; ++l) xv[l] = sval[l] ? xptr[l][0] : VOCABP;
    __syncthreads();                                   // table visible

    // ---- stage slab 0 into buf 0 ----
#pragma unroll
    for (int l = 0; l < 4; ++l) {
        if (l == 3 && tid >= STAGEN - 3 * 512) break;
        uint4 g = *(const uint4*)(tableL + xv[l] * 8);
        *(uint4*)((unsigned short*)As + loff[l]) = g;
    }
#pragma unroll
    for (int l = 0; l < 4; ++l) if (sval[l]) xv[l] = xptr[l][SLABP];
    LDS_BARRIER();

    // ---- B prefetch prologue: g=0,1 ----
    bf16x8 bc0[2], bc1[2], bc2[2] = {};
    bc0[0] = *(const bf16x8*)(Wtf + boff0);
    bc0[1] = *(const bf16x8*)(Wtf + boff1);
    bc1[0] = *(const bf16x8*)(Wtf + PLANE + boff0);
    bc1[1] = *(const bf16x8*)(Wtf + PLANE + boff1);

    int buf = 0;
    for (int s = 0; s < NSLAB; ++s) {
        // ---- stage slab s+1 into buf^1 ----
        if (s + 1 < NSLAB) {
            unsigned short* d = (unsigned short*)As + (buf ^ 1) * (BMR * AROWSH);
#pragma unroll
            for (int l = 0; l < 4; ++l) {
                if (l == 3 && tid >= STAGEN - 3 * 512) break;
                uint4 g = *(const uint4*)(tableL + xv[l] * 8);
                *(uint4*)(d + loff[l]) = g;
            }
        }
        // x for slab s+2 (a full slab of latency cover)
        if (s + 2 < NSLAB) {
#pragma unroll
            for (int l = 0; l < 4; ++l)
                if (sval[l]) xv[l] = xptr[l][(s + 2) * SLABP];
        }

        // ---- 5 BK=32 iterations; af ping-pong pipelined, B depth-2 ----
        const unsigned short* Asb = (const unsigned short*)As + buf * (BMR * AROWSH);
        bf16x8 afp[2][5];
#pragma unroll
        for (int i = 0; i < 5; ++i)
            afp[0][i] = *(const bf16x8*)(Asb + (i * 16 + r16) * AROWSH + q * 8);
#pragma unroll
        for (int kt = 0; kt < 5; ++kt) {
            if (kt < 4) {
#pragma unroll
                for (int i = 0; i < 5; ++i)
                    afp[(kt + 1) & 1][i] =
                        *(const bf16x8*)(Asb + (i * 16 + r16) * AROWSH + ((kt + 1) * 4 + q) * 8);
            }
            const int g = s * 5 + kt;
            if (g + 2 < NG) {
                const unsigned short* Wp = Wtf + (size_t)(g + 2) * PLANE;
                bc2[0] = *(const bf16x8*)(Wp + boff0);
                bc2[1] = *(const bf16x8*)(Wp + boff1);
            }
#pragma unroll
            for (int i = 0; i < 5; ++i) {
                acc[i][0] = __builtin_amdgcn_mfma_f32_16x16x32_bf16(afp[kt & 1][i], bc0[0], acc[i][0], 0, 0, 0);
                acc[i][1] = __builtin_amdgcn_mfma_f32_16x16x32_bf16(afp[kt & 1][i], bc0[1], acc[i][1], 0, 0, 0);
            }
            bc0[0] = bc1[0]; bc0[1] = bc1[1];
            bc1[0] = bc2[0]; bc1[1] = bc2[1];
        }
        LDS_BARRIER();
        buf ^= 1;
    }

    // ---- epilogue: gate + per-batch max in registers, atomicMax flush ----
    // C/D layout: col = lane&15 (n), row = q*4 + reg (m).
    const float b1v = b1[o], b2v = b2[o];
    float cur = 0.0f;
    int curb  = (m0 + q * 4) / TWIN;
#pragma unroll
    for (int i = 0; i < 5; ++i) {
#pragma unroll
        for (int rg = 0; rg < 4; ++rg) {
            const int row = m0 + i * 16 + q * 4 + rg;
            if (row < MROWS) {
                const int bb = row / TWIN;
                if (bb != curb) {
                    atomicMax((int*)&pool[curb * COUT + o], __float_as_int(cur));
                    cur = 0.0f; curb = bb;
                }
                const float c1 = acc[i][0][rg] + b1v;
                const float c2 = acc[i][1][rg] + b2v;
                const float g  = fmaxf(c1, 0.0f) / (1.0f + __expf(-c2));
                cur = fmaxf(cur, g);
            }
        }
    }
    atomicMax((int*)&pool[curb * COUT + o], __float_as_int(cur));

    // ---- last-block head: ticket, then 128x128 dense + sigmoid ----
    __shared__ unsigned int tick;
    __threadfence();                                   // order pool atomics before ticket
    __syncthreads();                                   // all waves' atomics drained
    if (tid == 0) tick = atomicAdd((unsigned int*)&pool[BATCH * COUT], 1u);
    __syncthreads();
    if (tick == NTILE - 1) {
        float* scratch = (float*)&As[0][0];            // reuse LDS: pl[1024] + hred[1024]
        float* pl   = scratch;
        float* hred = scratch + BATCH * COUT;
        for (int i = tid; i < BATCH * COUT; i += 512) {
            int old = atomicMax((int*)&pool[i], INT_MIN);  // coherent read, no modify
            pl[i] = __int_as_float(old);
        }
        __syncthreads();
        // 1024 (b,j) pairs over 512 threads
        for (int p = tid; p < BATCH * COUT; p += 512) {
            const int b = p >> 7, j = p & 127;
            float s = bd1[j];
            for (int i = 0; i < COUT; ++i) s += pl[b * COUT + i] * wd1[j * COUT + i];
            hred[p] = fmaxf(s, 0.0f) * wd2[j];
        }
        __syncthreads();
        if (tid < BATCH) {
            float s = 0.0f;
            for (int i = 0; i < COUT; ++i) s += hred[tid * COUT + i];
            out[tid] = 1.0f / (1.0f + expf(-(s + bd2[0])));
        }
    }
}

// ---------------- launch ----------------
extern "C" void kernel_launch(void* const* d_in, const int* in_sizes, int n_in,
                              void* d_out, int out_size, void* d_ws, size_t ws_size,
                              hipStream_t stream) {
    const int*   x   = (const int*)d_in[0];
    const float* emb = (const float*)d_in[1];
    const float* w1  = (const float*)d_in[2];
    const float* b1  = (const float*)d_in[3];
    const float* w2  = (const float*)d_in[4];
    const float* b2  = (const float*)d_in[5];
    const float* wd1 = (const float*)d_in[6];
    const float* bd1 = (const float*)d_in[7];
    const float* wd2 = (const float*)d_in[8];
    const float* bd2 = (const float*)d_in[9];
    float* out = (float*)d_out;

    unsigned short* Wtf  = (unsigned short*)((char*)d_ws + WTF_OFF);
    float*          pool = (float*)((char*)d_ws + POOL_OFF);

    wprep_kernel<<<dim3(NDIM), dim3(256), 0, stream>>>(w1, w2, Wtf, pool);
    gemm_kernel<<<dim3(NTILE), dim3(512), 0, stream>>>(x, emb, Wtf, b1, b2, pool,
                                                       wd1, bd1, wd2, bd2, out);
}

// Round 10
// 168.672 us; speedup vs baseline: 1.1090x; 1.1090x over previous
//
#include <hip/hip_runtime.h>

// ---------------- problem constants ----------------
#define BATCH   8
#define LSEQ    1048576          // 1<<20
#define KCONV   500
#define TWIN    2097             // (L-K)/K + 1
#define MROWS   16776            // BATCH*TWIN
#define KDIM    4000             // KCONV * C_IN
#define NDIM    256              // 2 * C_OUT
#define COUT    128
#define VOCAB   257
#define VOCABP  256              // padding row of emb (zeros)

#define BMR     80               // m-rows per block (5 x 16)
#define NTILE   210              // ceil(MROWS/80): fits 256 CUs, no serial tail
#define SLABP   20               // positions per slab = 160 k = 5 BK32 iters
#define NSLAB   25
#define NG      125              // total BK32 iterations
#define PLANE   (NDIM * 32)      // 8192 shorts per g-plane of Wtf
#define AROWSH  168              // padded shorts per A-slab row (160 + 8)
#define STAGEN  (BMR * SLABP)    // 1600 gathers per slab

// ---------------- ws layout (bytes) ----------------
#define WTF_OFF   0ull
#define WTF_BYTES ((size_t)NG * PLANE * 2)                  // 2,048,000
#define POOL_OFF  (WTF_OFF + WTF_BYTES)                     // 1024 floats

typedef __attribute__((ext_vector_type(8))) __bf16 bf16x8;
typedef __attribute__((ext_vector_type(4))) float  floatx4;

__device__ inline unsigned short f2bf(float f) {
    union { float f; unsigned u; } c; c.f = f;
    return (unsigned short)((c.u + 0x7FFFu + ((c.u >> 16) & 1u)) >> 16);
}
__device__ inline unsigned pack2(float lo, float hi) {
    return (unsigned)f2bf(lo) | ((unsigned)f2bf(hi) << 16);
}

// barrier that waits ONLY for LDS ops — leaves global (B/x prefetch) loads in flight
#define LDS_BARRIER() asm volatile("s_waitcnt lgkmcnt(0)\n\ts_barrier" ::: "memory")

// ---------------- kernel 1: frag-major weights + zero pool ----------------
// Wtf[g][n][kk] = w_n[e=(g*32+kk)&7][p=(g*32+kk)>>3]
__global__ __launch_bounds__(256) void wprep_kernel(const float* __restrict__ w1,
                                                    const float* __restrict__ w2,
                                                    unsigned short* __restrict__ Wtf,
                                                    float* __restrict__ pool) {
    const int n   = blockIdx.x;                        // 0..255
    const int tid = threadIdx.x;
    __shared__ float tile[KDIM];                       // 16 KB
    const float* src = (n < COUT) ? (w1 + (size_t)n * KDIM)
                                  : (w2 + (size_t)(n - COUT) * KDIM);
    for (int i = tid; i < KDIM; i += 256) tile[i] = src[i];
    __syncthreads();
    for (int i = tid; i < KDIM; i += 256) {
        int g = i >> 5, kk = i & 31;
        Wtf[(size_t)g * PLANE + n * 32 + kk] = f2bf(tile[(i & 7) * KCONV + (i >> 3)]);
    }
    if (n == 0 && tid < BATCH * COUT / 2)
        ((float2*)pool)[tid] = float2{0.f, 0.f};
}

// ---------------- kernel 2: fused embed + full-K GEMM + gate + max-pool ----------------
// Grid 210 x 512 thr (8 waves). Wave wv, lane (r16,q): o = wv*16 + r16 (0..127);
// acc[i][0]=c1, acc[i][1]=c2 (n=o+128) -> gate fully in registers.
// A: LDS emb table (gathers via the 32-bank crossbar, not the L1/TA path).
//    Slab double-buffered. KEY ORDERING (lgkm returns in-order per wave):
//    compute the 5 kt's FIRST, then issue next-slab staging, then LDS_BARRIER —
//    so kt=0's af waits cover only 5 ds_reads, and the staging burst drains
//    while being last before the barrier (r8 had staging first: every slab's
//    first MFMA transitively waited on the whole ~700-cyc staging burst).
// B: frag-major Wtf, coalesced 1KB register loads, depth-2 prefetch; LDS_BARRIER
//    (lgkm-only) never drains them. x prefetched a full slab ahead on vmcnt.
__global__ __launch_bounds__(512) void gemm_kernel(const int* __restrict__ x,
                                                   const float* __restrict__ emb,
                                                   const unsigned short* __restrict__ Wtf,
                                                   const float* __restrict__ b1,
                                                   const float* __restrict__ b2,
                                                   float* __restrict__ pool) {
    __shared__ unsigned short tableL[VOCAB * 8];       // 4112 B
    __shared__ unsigned short As[2][BMR * AROWSH];     // 2 x 26.25 KB

    const int tid  = threadIdx.x;
    const int lane = tid & 63;
    const int wv   = tid >> 6;                         // 0..7
    const int m0   = blockIdx.x * BMR;
    const int r16  = lane & 15;
    const int q    = lane >> 4;                        // 0..3

    // ---- build bf16 emb table in LDS ----
    if (tid < VOCAB) {
        const float4* er = (const float4*)(emb + tid * 8);
        float4 a = er[0], b = er[1];
        uint4 u;
        u.x = pack2(a.x, a.y); u.y = pack2(a.z, a.w);
        u.z = pack2(b.x, b.y); u.w = pack2(b.z, b.w);
        *(uint4*)(tableL + tid * 8) = u;
    }

    // ---- staging roles: thread handles idx = tid + 512*l (idx < 1600) ----
    const int* xptr[4];
    int        loff[4];
    bool       sval[4];
#pragma unroll
    for (int l = 0; l < 4; ++l) {
        int idx = tid + 512 * l;
        sval[l] = (idx < STAGEN);
        int ic  = sval[l] ? idx : 0;
        int row = ic / SLABP;
        int pos = ic - row * SLABP;
        int am  = m0 + row;
        bool av = sval[l] && (am < MROWS);
        sval[l] = av;
        int amc = av ? am : 0;
        int b   = amc / TWIN;
        int t   = amc - b * TWIN;
        xptr[l] = x + ((size_t)b * LSEQ + (size_t)t * KCONV + pos);
        loff[l] = row * AROWSH + pos * 8;
    }

    // ---- compute role ----
    const int o = wv * 16 + r16;                       // 0..127
    const size_t boff0 = (size_t)o * 32 + q * 8;
    const size_t boff1 = (size_t)(o + 128) * 32 + q * 8;

    floatx4 acc[5][2];
#pragma unroll
    for (int i = 0; i < 5; ++i) { acc[i][0] = floatx4{0,0,0,0}; acc[i][1] = floatx4{0,0,0,0}; }

    // ---- x values for slab 0 ----
    int xv[4], xn[4];
#pragma unroll
    for (int l = 0; l < 4; ++l) xv[l] = sval[l] ? xptr[l][0] : VOCABP;
    __syncthreads();                                   // table visible

    // ---- stage slab 0 into buf 0 (unavoidably before first compute) ----
#pragma unroll
    for (int l = 0; l < 4; ++l) {
        if (l == 3 && tid >= STAGEN - 3 * 512) break;
        uint4 g = *(const uint4*)(tableL + xv[l] * 8);
        *(uint4*)((unsigned short*)As + loff[l]) = g;
    }
#pragma unroll
    for (int l = 0; l < 4; ++l) xv[l] = sval[l] ? xptr[l][SLABP] : VOCABP;
    LDS_BARRIER();

    // ---- B prefetch prologue: g=0,1 ----
    bf16x8 bc0[2], bc1[2], bc2[2] = {};
    bc0[0] = *(const bf16x8*)(Wtf + boff0);
    bc0[1] = *(const bf16x8*)(Wtf + boff1);
    bc1[0] = *(const bf16x8*)(Wtf + PLANE + boff0);
    bc1[1] = *(const bf16x8*)(Wtf + PLANE + boff1);

    int buf = 0;
    for (int s = 0; s < NSLAB; ++s) {
        // issue x loads for slab s+2 early (vmcnt; a full slab of cover)
        if (s + 2 < NSLAB) {
#pragma unroll
            for (int l = 0; l < 4; ++l)
                xn[l] = sval[l] ? xptr[l][(s + 2) * SLABP] : VOCABP;
        }

        // ---- 5 BK=32 iterations from As[buf]; B depth-2 register pipeline ----
        const unsigned short* Asb = (const unsigned short*)As + buf * (BMR * AROWSH);
#pragma unroll
        for (int kt = 0; kt < 5; ++kt) {
            const int g = s * 5 + kt;
            if (g + 2 < NG) {
                const unsigned short* Wp = Wtf + (size_t)(g + 2) * PLANE;
                bc2[0] = *(const bf16x8*)(Wp + boff0);
                bc2[1] = *(const bf16x8*)(Wp + boff1);
            }
            bf16x8 af[5];
#pragma unroll
            for (int i = 0; i < 5; ++i)
                af[i] = *(const bf16x8*)(Asb + (i * 16 + r16) * AROWSH + (kt * 4 + q) * 8);
#pragma unroll
            for (int i = 0; i < 5; ++i) {
                acc[i][0] = __builtin_amdgcn_mfma_f32_16x16x32_bf16(af[i], bc0[0], acc[i][0], 0, 0, 0);
                acc[i][1] = __builtin_amdgcn_mfma_f32_16x16x32_bf16(af[i], bc0[1], acc[i][1], 0, 0, 0);
            }
            bc0[0] = bc1[0]; bc0[1] = bc1[1];
            bc1[0] = bc2[0]; bc1[1] = bc2[1];
        }

        // ---- NOW stage slab s+1 into buf^1 (drains into the barrier) ----
        if (s + 1 < NSLAB) {
            unsigned short* d = (unsigned short*)As + (buf ^ 1) * (BMR * AROWSH);
#pragma unroll
            for (int l = 0; l < 4; ++l) {
                if (l == 3 && tid >= STAGEN - 3 * 512) break;
                uint4 g = *(const uint4*)(tableL + xv[l] * 8);
                *(uint4*)(d + loff[l]) = g;
            }
        }
#pragma unroll
        for (int l = 0; l < 4; ++l) xv[l] = xn[l];
        LDS_BARRIER();
        buf ^= 1;
    }

    // ---- epilogue: gate + per-batch max in registers, atomicMax flush ----
    // C/D layout: col = lane&15 (n), row = q*4 + reg (m).
    const float b1v = b1[o], b2v = b2[o];
    float cur = 0.0f;
    int curb  = (m0 + q * 4) / TWIN;
#pragma unroll
    for (int i = 0; i < 5; ++i) {
#pragma unroll
        for (int rg = 0; rg < 4; ++rg) {
            const int row = m0 + i * 16 + q * 4 + rg;
            if (row < MROWS) {
                const int bb = row / TWIN;
                if (bb != curb) {
                    atomicMax((int*)&pool[curb * COUT + o], __float_as_int(cur));
                    cur = 0.0f; curb = bb;
                }
                const float c1 = acc[i][0][rg] + b1v;
                const float c2 = acc[i][1][rg] + b2v;
                const float g  = fmaxf(c1, 0.0f) / (1.0f + __expf(-c2));
                cur = fmaxf(cur, g);
            }
        }
    }
    atomicMax((int*)&pool[curb * COUT + o], __float_as_int(cur));
}

// ---------------- kernel 3: dense head ----------------
__global__ __launch_bounds__(128) void head_kernel(const float* __restrict__ pool,
                                                   const float* __restrict__ wd1,
                                                   const float* __restrict__ bd1,
                                                   const float* __restrict__ wd2,
                                                   const float* __restrict__ bd2,
                                                   float* __restrict__ out) {
    __shared__ float red[BATCH][COUT];
    int j = threadIdx.x;                               // 0..127
    float wj = wd2[j];
#pragma unroll
    for (int b = 0; b < BATCH; ++b) {
        float s = bd1[j];
        for (int i = 0; i < COUT; ++i) s += pool[b * COUT + i] * wd1[j * COUT + i];
        red[b][j] = fmaxf(s, 0.0f) * wj;
    }
    __syncthreads();
    if (j < BATCH) {
        float s = 0.0f;
        for (int i = 0; i < COUT; ++i) s += red[j][i];
        out[j] = 1.0f / (1.0f + expf(-(s + bd2[0])));
    }
}

// ---------------- launch ----------------
extern "C" void kernel_launch(void* const* d_in, const int* in_sizes, int n_in,
                              void* d_out, int out_size, void* d_ws, size_t ws_size,
                              hipStream_t stream) {
    const int*   x   = (const int*)d_in[0];
    const float* emb = (const float*)d_in[1];
    const float* w1  = (const float*)d_in[2];
    const float* b1  = (const float*)d_in[3];
    const float* w2  = (const float*)d_in[4];
    const float* b2  = (const float*)d_in[5];
    const float* wd1 = (const float*)d_in[6];
    const float* bd1 = (const float*)d_in[7];
    const float* wd2 = (const float*)d_in[8];
    const float* bd2 = (const float*)d_in[9];
    float* out = (float*)d_out;

    unsigned short* Wtf  = (unsigned short*)((char*)d_ws + WTF_OFF);
    float*          pool = (float*)((char*)d_ws + POOL_OFF);

    wprep_kernel<<<dim3(NDIM), dim3(256), 0, stream>>>(w1, w2, Wtf, pool);
    gemm_kernel<<<dim3(NTILE), dim3(512), 0, stream>>>(x, emb, Wtf, b1, b2, pool);
    head_kernel<<<dim3(1), dim3(128), 0, stream>>>(pool, wd1, bd1, wd2, bd2, out);
}